// Round 1
// baseline (392.313 us; speedup 1.0000x reference)
//
#include <hip/hip_runtime.h>
#include <math.h>

#define HOP       128
#define NBINS     257
#define NFRAMES   4000
#define NB        16
#define OUT_LEN   512383          // (4000-1)*128 + 512 - 1
#define CPR       8               // chunks per range (per wave)
#define RPB       501             // ranges per batch = ceil(4003/8)
#define NCHUNK    4003            // output chunks of 128 (last has 127 samples)
#define PBF       320             // per-wave LDS scratch (float2) per buffer

__device__ __forceinline__ float2 cmul(float2 a, float2 b) {
    return make_float2(a.x*b.x - a.y*b.y, a.x*b.y + a.y*b.x);
}

// Inverse-sign DFT4: y[t] = sum_j x[j] * i^(j*t)
__device__ __forceinline__ void dft4(const float2* x, float2* y) {
    const float s0r=x[0].x+x[2].x, s0i=x[0].y+x[2].y;
    const float d0r=x[0].x-x[2].x, d0i=x[0].y-x[2].y;
    const float s1r=x[1].x+x[3].x, s1i=x[1].y+x[3].y;
    const float d1r=x[1].x-x[3].x, d1i=x[1].y-x[3].y;
    y[0]=make_float2(s0r+s1r, s0i+s1i);
    y[2]=make_float2(s0r-s1r, s0i-s1i);
    y[1]=make_float2(d0r-d1i, d0i+d1r);   // d0 + i*d1
    y[3]=make_float2(d0r+d1i, d0i-d1r);   // d0 - i*d1
}

// Real-packed iSTFT, software-pipelined: packed 256-pt inverse FFT per frame
// (4 in-lane DFT4 stages, 3 LDS transposes), double-buffered LDS so frame
// f+1's global loads + stage1 overlap frame f's LDS round-trip stalls.
// One wave per 8-chunk range (+3 halo frames); register OLA; no atomics,
// no barriers of any kind.
//
// launch_bounds(256, 8): force VGPR<=64 so 8 waves/SIMD are resident
// (at 68 VGPRs occupancy halves to 4/SIMD; kernel is LDS-latency-bound).
// ctw[] and half of wwx/wwy are rematerialized per frame to give the
// allocator slack (~10 regs) so the cap doesn't induce scratch spills.
__global__ __launch_bounds__(256, 8)
void istft_pk2_kernel(const float* __restrict__ re,
                      const float* __restrict__ im,
                      float* __restrict__ out)
{
    __shared__ float2 bufA[4][PBF];   // 2 * 4 * 2560 B = 20480 B / block
    __shared__ float2 bufB[4][PBF];

    const int tid = threadIdx.x;
    const int wv  = tid >> 6;
    const int l   = tid & 63;
    float2* PA = bufA[wv];
    float2* PBp = bufB[wv];

    const int rid = blockIdx.x * 4 + wv;     // 0..8015 exact
    const int b   = rid / RPB;
    const int rr  = rid - b * RPB;
    const int c0  = rr * CPR;
    const int fend = min(c0 + CPR - 1, NCHUNK - 1);

    const float* __restrict__ reb = re + (size_t)b * NFRAMES * NBINS;
    const float* __restrict__ imb = im + (size_t)b * NFRAMES * NBINS;
    float* __restrict__ outb = out + (size_t)b * OUT_LEN;

    // ---- frame-invariant per-lane constants ----
    const float TWO_PI = 6.2831853071795864f;
    const float RQ = 0.70710678118654752f;
    // Pack twiddle seed: e^{2 pi i l/512}; j-step (+64 bins) rotates by pi/4,
    // regenerated inside stage1 instead of keeping ctw[1..3] live (saves 6 VGPRs).
    float2 ctw0;
    { float s, c; __sincosf(TWO_PI * (float)l * (1.0f/512.0f), &s, &c);
      ctw0 = make_float2(c, s); }
    float2 w1, w2, w3;
    { float s, c; __sincosf(TWO_PI * (float)l * (1.0f/256.0f), &s, &c);
      w1 = make_float2(c, s); w2 = cmul(w1, w1); w3 = cmul(w2, w1); }
    float2 b1, b2, b3;
    { float s, c; __sincosf(TWO_PI * (float)(l & 15) * (1.0f/64.0f), &s, &c);
      b1 = make_float2(c, s); b2 = cmul(b1, b1); b3 = cmul(b2, b1); }
    float2 q1, q2, q3;
    { float s, c; __sincosf(TWO_PI * (float)(l & 3) * (1.0f/16.0f), &s, &c);
      q1 = make_float2(c, s); q2 = cmul(q1, q1); q3 = cmul(q2, q1); }
    // Window weights for samples 2l+128o (x) and 2l+1+128o (y), o=0..3.
    // Hann identity: ww[2] = 2S - ww[0], ww[3] = 2S - ww[1] -> keep only o=0,1
    // (saves 4 VGPRs; o=2,3 applied as fma chains below).
    const float S2 = 1.3020833333e-3f;    // 2 * 0.5/768
    float wwx0, wwx1, wwy0, wwy1;
    {
        const float S = 6.5104166667e-4f;   // 0.5/768
        float sx, cx; __sincosf(TWO_PI * (float)(2*l) * (1.0f/512.0f), &sx, &cx);
        wwx0 = S*(1.0f-cx); wwx1 = S*(1.0f+sx);
        float sy, cy; __sincosf(TWO_PI * (float)(2*l+1) * (1.0f/512.0f), &sy, &cy);
        wwy0 = S*(1.0f-cy); wwy1 = S*(1.0f+sy);
    }
    // Conflict-free transpose layouts (float2 index; each bank-pair hit 4x/wave).
    const int a1w = l;                                        // + 64*t0
    const int a1r = (l & 15) + 64 * (l >> 4);                 // + 16*q
    const int a2w = (l & 15) + 20 * (l >> 4);                 // + 80*t1
    const int a2r = (l & 3) + 20 * ((l >> 2) & 3) + 80 * (l >> 4);   // + 4*r
    const int a3w = ((l >> 2) & 3) + 4 * (l >> 4) + 20 * (l & 3);    // + 80*t2
    const int a3r = (l & 3) + 4 * ((l >> 2) & 3) + 80 * (l >> 4);    // + 20*k0

    float accx[4], accy[4];
    #pragma unroll
    for (int o = 0; o < 4; ++o) { accx[o] = 0.0f; accy[o] = 0.0f; }

    // Raw prefetch registers for the next frame's inputs.
    float dr[4], di[4], mr4[4], mi4[4];

    auto issue_loads = [&](int fq) {
        const int fc = min(max(fq, 0), NFRAMES - 1);
        const float* __restrict__ rb = reb + (size_t)fc * NBINS;
        const float* __restrict__ ib = imb + (size_t)fc * NBINS;
        #pragma unroll
        for (int j = 0; j < 4; ++j) {
            const int k = l + 64*j, km = 256 - k;
            dr[j]  = rb[k];  di[j]  = ib[k];
            mr4[j] = rb[km]; mi4[j] = ib[km];
        }
    };

    auto stage1 = [&](float2* __restrict__ P) {
        // Pack C[k] = (Y[k]+conj(Y[256-k])) + i e^{2pi i k/512}(Y[k]-conj(Y[256-k]))
        float2 Cv[4];
        float cc = ctw0.x, ss = ctw0.y;   // walking twiddle, pi/4 per j-step
        #pragma unroll
        for (int j = 0; j < 4; ++j) {
            float ydr = dr[j], ydi = di[j], ymr = mr4[j], ymi = mi4[j];
            if (j == 0) {                       // k==0: Im of DC & Nyquist ignored
                const bool z = (l == 0);
                ydi = z ? 0.0f : ydi;
                ymi = z ? 0.0f : ymi;
            }
            const float er  = ydr + ymr, ei  = ydi - ymi;
            const float fr2 = ydr - ymr, fi2 = ydi + ymi;
            const float gr = cc*fr2 - ss*fi2;
            const float gi = cc*fi2 + ss*fr2;
            Cv[j] = make_float2(er - gi, ei + gr);
            const float cn = (cc - ss) * RQ, sn = (ss + cc) * RQ;  // rotate pi/4
            cc = cn; ss = sn;
        }
        float2 A[4];
        dft4(Cv, A);
        A[1] = cmul(A[1], w1); A[2] = cmul(A[2], w2); A[3] = cmul(A[3], w3);
        P[a1w] = A[0]; P[a1w+64] = A[1]; P[a1w+128] = A[2]; P[a1w+192] = A[3];
    };

    auto stages234 = [&](float2* __restrict__ P, int f) {
        float2 A[4], G[4];
        G[0] = P[a1r]; G[1] = P[a1r+16]; G[2] = P[a1r+32]; G[3] = P[a1r+48];
        dft4(G, A);
        A[1] = cmul(A[1], b1); A[2] = cmul(A[2], b2); A[3] = cmul(A[3], b3);
        P[a2w] = A[0]; P[a2w+80] = A[1]; P[a2w+160] = A[2]; P[a2w+240] = A[3];
        G[0] = P[a2r]; G[1] = P[a2r+4]; G[2] = P[a2r+8]; G[3] = P[a2r+12];
        dft4(G, A);
        A[1] = cmul(A[1], q1); A[2] = cmul(A[2], q2); A[3] = cmul(A[3], q3);
        P[a3w] = A[0]; P[a3w+80] = A[1]; P[a3w+160] = A[2]; P[a3w+240] = A[3];
        G[0] = P[a3r]; G[1] = P[a3r+20]; G[2] = P[a3r+40]; G[3] = P[a3r+60];
        dft4(G, A);
        if (f >= 0 && f < NFRAMES) {            // wave-uniform gate
            // o=0,1 use live weights; o=2,3 via Hann identity 2S - ww (fma form,
            // deliberately not hoistable so no extra persistent registers).
            accx[0] = fmaf(A[0].x, wwx0, accx[0]);
            accx[1] = fmaf(A[1].x, wwx1, accx[1]);
            accx[2] = fmaf(A[2].x, S2, fmaf(-A[2].x, wwx0, accx[2]));
            accx[3] = fmaf(A[3].x, S2, fmaf(-A[3].x, wwx1, accx[3]));
            accy[0] = fmaf(A[0].y, wwy0, accy[0]);
            accy[1] = fmaf(A[1].y, wwy1, accy[1]);
            accy[2] = fmaf(A[2].y, S2, fmaf(-A[2].y, wwy0, accy[2]));
            accy[3] = fmaf(A[3].y, S2, fmaf(-A[3].y, wwy1, accy[3]));
        }
        if (f >= c0) {                          // emit chunk f (complete now)
            const int s0 = f * HOP + 2*l;       // max 512382 < OUT_LEN
            outb[s0] = accx[0];
            const int s1 = s0 + 1;              // == OUT_LEN only at the very end
            if (s1 < OUT_LEN) outb[s1] = accy[0];
        }
        #pragma unroll
        for (int o = 0; o < 3; ++o) { accx[o] = accx[o+1]; accy[o] = accy[o+1]; }
        accx[3] = 0.0f; accy[3] = 0.0f;
    };

    // ---- software-pipelined frame loop ----
    issue_loads(c0 - 3);
    stage1(PA);
    for (int f = c0 - 3; f <= fend; f += 2) {
        issue_loads(f + 1);      // in flight during stages234(f)
        stages234(PA, f);
        stage1(PBp);             // consumes f+1 loads
        if (f + 1 <= fend) {
            issue_loads(f + 2);
            stages234(PBp, f + 1);
            stage1(PA);
        }
    }
}

extern "C" void kernel_launch(void* const* d_in, const int* in_sizes, int n_in,
                              void* d_out, int out_size, void* d_ws, size_t ws_size,
                              hipStream_t stream) {
    (void)in_sizes; (void)n_in; (void)d_ws; (void)ws_size; (void)out_size;
    const float* re = (const float*)d_in[0];
    const float* im = (const float*)d_in[1];
    float* out = (float*)d_out;

    // 16 batches x 501 ranges = 8016 waves; 4 waves per 256-thread block.
    // At <=64 VGPR + 20480 B LDS the whole grid is co-resident (8 blocks/CU).
    const int nblocks = (NB * RPB) / 4;   // 2004
    istft_pk2_kernel<<<dim3(nblocks), dim3(256), 0, stream>>>(re, im, out);
}

// Round 2
// 247.646 us; speedup vs baseline: 1.5842x; 1.5842x over previous
//
#include <hip/hip_runtime.h>
#include <math.h>

#define HOP       128
#define NBINS     257
#define NFRAMES   4000
#define NB        16
#define OUT_LEN   512383          // (4000-1)*128 + 512 - 1
#define CPR       8               // chunks per range (per wave)
#define RPB       501             // ranges per batch = ceil(4003/8)
#define NCHUNK    4003            // output chunks of 128 (last has 127 samples)
#define PBF4      320             // per-wave LDS scratch (float4) per buffer

__device__ __forceinline__ float2 cmul(float2 a, float2 b) {
    return make_float2(a.x*b.x - a.y*b.y, a.x*b.y + a.y*b.x);
}

// Inverse-sign DFT4: y[t] = sum_j x[j] * i^(j*t)
__device__ __forceinline__ void dft4(const float2* x, float2* y) {
    const float s0r=x[0].x+x[2].x, s0i=x[0].y+x[2].y;
    const float d0r=x[0].x-x[2].x, d0i=x[0].y-x[2].y;
    const float s1r=x[1].x+x[3].x, s1i=x[1].y+x[3].y;
    const float d1r=x[1].x-x[3].x, d1i=x[1].y-x[3].y;
    y[0]=make_float2(s0r+s1r, s0i+s1i);
    y[2]=make_float2(s0r-s1r, s0i-s1i);
    y[1]=make_float2(d0r-d1i, d0i+d1r);   // d0 + i*d1
    y[3]=make_float2(d0r+d1i, d0i-d1r);   // d0 - i*d1
}

// Real-packed iSTFT, 2-frame-paired: each FFT pass computes TWO frames'
// packed 256-pt inverse FFTs, frame pair interleaved as .xy/.zw of float4
// LDS slots (b128 transposes). Rationale: round-0 profile showed the kernel
// latency-bound on 3 dependent LDS round-trips/frame (VALUBusy 33%, occ 27%,
// 0 bank conflicts); pairing doubles VALU work per round-trip at ZERO
// occupancy cost (68->~110 VGPR stays in the 65..128 / 4-waves-per-SIMD band).
// Round-1 post-mortem: forcing <=64 VGPR (8 waves/SIMD) spills catastrophically
// (FETCH 95->710 MB, 293 us) -- occupancy is NOT the lever here, ILP is.
// One wave per 8-chunk range (+3 halo frames); register OLA; no barriers.
__global__ __launch_bounds__(256, 4)
void istft_pk4_kernel(const float* __restrict__ re,
                      const float* __restrict__ im,
                      float* __restrict__ out)
{
    __shared__ float4 bufA[4][PBF4];   // 4 waves * 320 * 16 B = 20480 B
    __shared__ float4 bufB[4][PBF4];   // total 40960 B / block

    const int tid = threadIdx.x;
    const int wv  = tid >> 6;
    const int l   = tid & 63;
    float4* PA = bufA[wv];
    float4* PBp = bufB[wv];

    const int rid = blockIdx.x * 4 + wv;     // 0..8015 exact
    const int b   = rid / RPB;
    const int rr  = rid - b * RPB;
    const int c0  = rr * CPR;
    const int fend = min(c0 + CPR - 1, NCHUNK - 1);

    const float* __restrict__ reb = re + (size_t)b * NFRAMES * NBINS;
    const float* __restrict__ imb = im + (size_t)b * NFRAMES * NBINS;
    float* __restrict__ outb = out + (size_t)b * OUT_LEN;

    // ---- frame-invariant per-lane constants (shared by both frames of a pair) ----
    const float TWO_PI = 6.2831853071795864f;
    const float RQ = 0.70710678118654752f;
    // Pack twiddle seed e^{2 pi i l/512}; +64-bin step = pi/4 rotation,
    // walked inside stage1 (keeps only 2 persistent regs).
    float2 ctw0;
    { float s, c; __sincosf(TWO_PI * (float)l * (1.0f/512.0f), &s, &c);
      ctw0 = make_float2(c, s); }
    float2 w1, w2, w3;
    { float s, c; __sincosf(TWO_PI * (float)l * (1.0f/256.0f), &s, &c);
      w1 = make_float2(c, s); w2 = cmul(w1, w1); w3 = cmul(w2, w1); }
    float2 b1, b2, b3;
    { float s, c; __sincosf(TWO_PI * (float)(l & 15) * (1.0f/64.0f), &s, &c);
      b1 = make_float2(c, s); b2 = cmul(b1, b1); b3 = cmul(b2, b1); }
    float2 q1, q2, q3;
    { float s, c; __sincosf(TWO_PI * (float)(l & 3) * (1.0f/16.0f), &s, &c);
      q1 = make_float2(c, s); q2 = cmul(q1, q1); q3 = cmul(q2, q1); }
    // Window weights for samples 2l+128o (x) / 2l+1+128o (y); Hann identity
    // ww[2]=2S-ww[0], ww[3]=2S-ww[1] keeps only o=0,1 persistent.
    const float S2 = 1.3020833333e-3f;    // 2 * 0.5/768
    float wwx0, wwx1, wwy0, wwy1;
    {
        const float S = 6.5104166667e-4f;   // 0.5/768
        float sx, cx; __sincosf(TWO_PI * (float)(2*l) * (1.0f/512.0f), &sx, &cx);
        wwx0 = S*(1.0f-cx); wwx1 = S*(1.0f+sx);
        float sy, cy; __sincosf(TWO_PI * (float)(2*l+1) * (1.0f/512.0f), &sy, &cy);
        wwy0 = S*(1.0f-cy); wwy1 = S*(1.0f+sy);
    }
    // Transpose layouts (float4 index now; same index algebra as the proven
    // conflict-free b64 version, each 16-lane group reads/writes a contiguous
    // 256 B run -> <=2-way bank aliasing on b128, free per m136).
    const int a1w = l;                                        // + 64*t0
    const int a1r = (l & 15) + 64 * (l >> 4);                 // + 16*q
    const int a2w = (l & 15) + 20 * (l >> 4);                 // + 80*t1
    const int a2r = (l & 3) + 20 * ((l >> 2) & 3) + 80 * (l >> 4);   // + 4*r
    const int a3w = ((l >> 2) & 3) + 4 * (l >> 4) + 20 * (l & 3);    // + 80*t2
    const int a3r = (l & 3) + 4 * ((l >> 2) & 3) + 80 * (l >> 4);    // + 20*k0

    float accx[4], accy[4];
    #pragma unroll
    for (int o = 0; o < 4; ++o) { accx[o] = 0.0f; accy[o] = 0.0f; }

    // Raw prefetch registers for the next PAIR of frames.
    float dra[4], dia[4], mra[4], mia[4];
    float drb[4], dib[4], mrb[4], mib[4];

    auto issue_loads = [&](int fq) {           // frames fq (a) and fq+1 (b)
        const int fca = min(max(fq,     0), NFRAMES - 1);
        const int fcb = min(max(fq + 1, 0), NFRAMES - 1);
        const float* __restrict__ rba = reb + (size_t)fca * NBINS;
        const float* __restrict__ iba = imb + (size_t)fca * NBINS;
        const float* __restrict__ rbb = reb + (size_t)fcb * NBINS;
        const float* __restrict__ ibb = imb + (size_t)fcb * NBINS;
        #pragma unroll
        for (int j = 0; j < 4; ++j) {
            const int k = l + 64*j, km = 256 - k;
            dra[j] = rba[k];  dia[j] = iba[k];
            mra[j] = rba[km]; mia[j] = iba[km];
            drb[j] = rbb[k];  dib[j] = ibb[k];
            mrb[j] = rbb[km]; mib[j] = ibb[km];
        }
    };

    // Stage-1 math for one frame: pack + dft4 + w-twiddles -> A[4].
    auto s1frame = [&](const float* dr_, const float* di_,
                       const float* mr_, const float* mi_, float2* A) {
        float2 Cv[4];
        float cc = ctw0.x, ss = ctw0.y;   // walking twiddle, pi/4 per j-step
        #pragma unroll
        for (int j = 0; j < 4; ++j) {
            float ydr = dr_[j], ydi = di_[j], ymr = mr_[j], ymi = mi_[j];
            if (j == 0) {                       // k==0: Im of DC & Nyquist ignored
                const bool z = (l == 0);
                ydi = z ? 0.0f : ydi;
                ymi = z ? 0.0f : ymi;
            }
            const float er  = ydr + ymr, ei  = ydi - ymi;
            const float fr2 = ydr - ymr, fi2 = ydi + ymi;
            const float gr = cc*fr2 - ss*fi2;
            const float gi = cc*fi2 + ss*fr2;
            Cv[j] = make_float2(er - gi, ei + gr);
            const float cn = (cc - ss) * RQ, sn = (ss + cc) * RQ;  // rotate pi/4
            cc = cn; ss = sn;
        }
        dft4(Cv, A);
        A[1] = cmul(A[1], w1); A[2] = cmul(A[2], w2); A[3] = cmul(A[3], w3);
    };

    auto stage1 = [&](float4* __restrict__ P) {
        float2 Aa[4], Ab[4];
        s1frame(dra, dia, mra, mia, Aa);
        s1frame(drb, dib, mrb, mib, Ab);
        #pragma unroll
        for (int j = 0; j < 4; ++j)
            P[a1w + 64*j] = make_float4(Aa[j].x, Aa[j].y, Ab[j].x, Ab[j].y);
    };

    auto stages234 = [&](float4* __restrict__ P, int fa) {
        float2 Ga[4], Gb[4], Aa[4], Ab[4];
        // ---- stage 2 ----
        #pragma unroll
        for (int t = 0; t < 4; ++t) {
            const float4 g = P[a1r + 16*t];
            Ga[t] = make_float2(g.x, g.y); Gb[t] = make_float2(g.z, g.w);
        }
        dft4(Ga, Aa); dft4(Gb, Ab);
        Aa[1]=cmul(Aa[1],b1); Aa[2]=cmul(Aa[2],b2); Aa[3]=cmul(Aa[3],b3);
        Ab[1]=cmul(Ab[1],b1); Ab[2]=cmul(Ab[2],b2); Ab[3]=cmul(Ab[3],b3);
        #pragma unroll
        for (int t = 0; t < 4; ++t)
            P[a2w + 80*t] = make_float4(Aa[t].x, Aa[t].y, Ab[t].x, Ab[t].y);
        // ---- stage 3 ----
        #pragma unroll
        for (int t = 0; t < 4; ++t) {
            const float4 g = P[a2r + 4*t];
            Ga[t] = make_float2(g.x, g.y); Gb[t] = make_float2(g.z, g.w);
        }
        dft4(Ga, Aa); dft4(Gb, Ab);
        Aa[1]=cmul(Aa[1],q1); Aa[2]=cmul(Aa[2],q2); Aa[3]=cmul(Aa[3],q3);
        Ab[1]=cmul(Ab[1],q1); Ab[2]=cmul(Ab[2],q2); Ab[3]=cmul(Ab[3],q3);
        #pragma unroll
        for (int t = 0; t < 4; ++t)
            P[a3w + 80*t] = make_float4(Aa[t].x, Aa[t].y, Ab[t].x, Ab[t].y);
        // ---- stage 4 ----
        #pragma unroll
        for (int t = 0; t < 4; ++t) {
            const float4 g = P[a3r + 20*t];
            Ga[t] = make_float2(g.x, g.y); Gb[t] = make_float2(g.z, g.w);
        }
        dft4(Ga, Aa); dft4(Gb, Ab);
        // ---- OLA: frame fa first (chunk fa must NOT see frame fb), then fb ----
        const int fb = fa + 1;
        if (fa >= 0 && fa < NFRAMES) {          // wave-uniform gate
            accx[0] = fmaf(Aa[0].x, wwx0, accx[0]);
            accx[1] = fmaf(Aa[1].x, wwx1, accx[1]);
            accx[2] = fmaf(Aa[2].x, S2, fmaf(-Aa[2].x, wwx0, accx[2]));
            accx[3] = fmaf(Aa[3].x, S2, fmaf(-Aa[3].x, wwx1, accx[3]));
            accy[0] = fmaf(Aa[0].y, wwy0, accy[0]);
            accy[1] = fmaf(Aa[1].y, wwy1, accy[1]);
            accy[2] = fmaf(Aa[2].y, S2, fmaf(-Aa[2].y, wwy0, accy[2]));
            accy[3] = fmaf(Aa[3].y, S2, fmaf(-Aa[3].y, wwy1, accy[3]));
        }
        if (fa >= c0 && fa <= fend) {           // emit chunk fa (complete now)
            const int s0 = fa * HOP + 2*l;      // max 512382 < OUT_LEN
            outb[s0] = accx[0];
            const int s1 = s0 + 1;
            if (s1 < OUT_LEN) outb[s1] = accy[0];
        }
        #pragma unroll
        for (int o = 0; o < 3; ++o) { accx[o] = accx[o+1]; accy[o] = accy[o+1]; }
        accx[3] = 0.0f; accy[3] = 0.0f;
        if (fb >= 0 && fb < NFRAMES) {
            accx[0] = fmaf(Ab[0].x, wwx0, accx[0]);
            accx[1] = fmaf(Ab[1].x, wwx1, accx[1]);
            accx[2] = fmaf(Ab[2].x, S2, fmaf(-Ab[2].x, wwx0, accx[2]));
            accx[3] = fmaf(Ab[3].x, S2, fmaf(-Ab[3].x, wwx1, accx[3]));
            accy[0] = fmaf(Ab[0].y, wwy0, accy[0]);
            accy[1] = fmaf(Ab[1].y, wwy1, accy[1]);
            accy[2] = fmaf(Ab[2].y, S2, fmaf(-Ab[2].y, wwy0, accy[2]));
            accy[3] = fmaf(Ab[3].y, S2, fmaf(-Ab[3].y, wwy1, accy[3]));
        }
        if (fb >= c0 && fb <= fend) {
            const int s0 = fb * HOP + 2*l;
            outb[s0] = accx[0];
            const int s1 = s0 + 1;
            if (s1 < OUT_LEN) outb[s1] = accy[0];
        }
        #pragma unroll
        for (int o = 0; o < 3; ++o) { accx[o] = accx[o+1]; accy[o] = accy[o+1]; }
        accx[3] = 0.0f; accy[3] = 0.0f;
    };

    // ---- software-pipelined pair loop: 6 pairs = frames c0-4 .. c0+7 ----
    // (frame c0-4 contributes only to chunks < c0: harmless 1-frame halo waste;
    //  frames > fend are load-clamped + acc/emit-gated.)
    const int base = c0 - 4;
    issue_loads(base);
    stage1(PA);
    #pragma unroll 1
    for (int p = 0; p < 6; p += 2) {
        issue_loads(base + 2*(p+1));   // in flight during stages234(pair p)
        stages234(PA, base + 2*p);
        stage1(PBp);                   // consumes pair p+1 loads
        if (p + 2 < 6) issue_loads(base + 2*(p+2));
        stages234(PBp, base + 2*(p+1));
        if (p + 2 < 6) stage1(PA);
    }
}

extern "C" void kernel_launch(void* const* d_in, const int* in_sizes, int n_in,
                              void* d_out, int out_size, void* d_ws, size_t ws_size,
                              hipStream_t stream) {
    (void)in_sizes; (void)n_in; (void)d_ws; (void)ws_size; (void)out_size;
    const float* re = (const float*)d_in[0];
    const float* im = (const float*)d_in[1];
    float* out = (float*)d_out;

    // 16 batches x 501 ranges = 8016 waves; 4 waves per 256-thread block.
    const int nblocks = (NB * RPB) / 4;   // 2004
    istft_pk4_kernel<<<dim3(nblocks), dim3(256), 0, stream>>>(re, im, out);
}

// Round 3
// 172.027 us; speedup vs baseline: 2.2805x; 1.4396x over previous
//
#include <hip/hip_runtime.h>
#include <math.h>

#define HOP       128
#define NBINS     257
#define NFRAMES   4000
#define NB        16
#define OUT_LEN   512383          // (4000-1)*128 + 512 - 1
#define CPR       8               // chunks per range (per wave)
#define RPB       501             // ranges per batch = ceil(4003/8)
#define NCHUNK    4003            // output chunks of 128 (last has 127 samples)
#define PBF4      320             // per-wave LDS scratch (float4) per buffer

__device__ __forceinline__ float2 cmul(float2 a, float2 b) {
    return make_float2(a.x*b.x - a.y*b.y, a.x*b.y + a.y*b.x);
}

// Inverse-sign DFT4: y[t] = sum_j x[j] * i^(j*t)
__device__ __forceinline__ void dft4(const float2* x, float2* y) {
    const float s0r=x[0].x+x[2].x, s0i=x[0].y+x[2].y;
    const float d0r=x[0].x-x[2].x, d0i=x[0].y-x[2].y;
    const float s1r=x[1].x+x[3].x, s1i=x[1].y+x[3].y;
    const float d1r=x[1].x-x[3].x, d1i=x[1].y-x[3].y;
    y[0]=make_float2(s0r+s1r, s0i+s1i);
    y[2]=make_float2(s0r-s1r, s0i-s1i);
    y[1]=make_float2(d0r-d1i, d0i+d1r);   // d0 + i*d1
    y[3]=make_float2(d0r+d1i, d0i-d1r);   // d0 - i*d1
}

// Real-packed iSTFT, 2-frame-paired: each FFT pass computes TWO frames'
// packed 256-pt inverse FFTs, frame pair interleaved as .xy/.zw of float4
// LDS slots (b128 transposes). Round-0 profile: latency-bound on 3 dependent
// LDS round-trips/frame (VALUBusy 33%, occ 27%); pairing doubles VALU work
// per round-trip at zero occupancy cost.
//
// LAUNCH-BOUNDS LEDGER (hard-won, do not regress):
//   (256,8) -> compiler caps at 32 VGPR  -> catastrophic spill (293 us, r1)
//   (256,4) -> compiler caps at 64 VGPR  -> spill: FETCH 281 MB, WRITE 114 MB,
//              VALUBusy 17.5%, 160 us (r2)
//   empirical mapping on this toolchain: cap = 256 / min_waves_per_EU
//   (unified VGPR/AGPR budget split).  Kernel needs ~110-120 live VGPRs
//   => use (256,2): cap 128.  LDS (40960 B/block) already limits residency
//   to 4 blocks/CU = 4 waves/SIMD, so <=128 VGPR costs no occupancy.
__global__ __launch_bounds__(256, 2)
void istft_pk4_kernel(const float* __restrict__ re,
                      const float* __restrict__ im,
                      float* __restrict__ out)
{
    __shared__ float4 bufA[4][PBF4];   // 4 waves * 320 * 16 B = 20480 B
    __shared__ float4 bufB[4][PBF4];   // total 40960 B / block

    const int tid = threadIdx.x;
    const int wv  = tid >> 6;
    const int l   = tid & 63;
    float4* PA = bufA[wv];
    float4* PBp = bufB[wv];

    const int rid = blockIdx.x * 4 + wv;     // 0..8015 exact
    const int b   = rid / RPB;
    const int rr  = rid - b * RPB;
    const int c0  = rr * CPR;
    const int fend = min(c0 + CPR - 1, NCHUNK - 1);

    const float* __restrict__ reb = re + (size_t)b * NFRAMES * NBINS;
    const float* __restrict__ imb = im + (size_t)b * NFRAMES * NBINS;
    float* __restrict__ outb = out + (size_t)b * OUT_LEN;

    // ---- frame-invariant per-lane constants (shared by both frames of a pair) ----
    const float TWO_PI = 6.2831853071795864f;
    const float RQ = 0.70710678118654752f;
    // Pack twiddle seed e^{2 pi i l/512}; +64-bin step = pi/4 rotation,
    // walked inside stage1 (keeps only 2 persistent regs).
    float2 ctw0;
    { float s, c; __sincosf(TWO_PI * (float)l * (1.0f/512.0f), &s, &c);
      ctw0 = make_float2(c, s); }
    float2 w1, w2, w3;
    { float s, c; __sincosf(TWO_PI * (float)l * (1.0f/256.0f), &s, &c);
      w1 = make_float2(c, s); w2 = cmul(w1, w1); w3 = cmul(w2, w1); }
    float2 b1, b2, b3;
    { float s, c; __sincosf(TWO_PI * (float)(l & 15) * (1.0f/64.0f), &s, &c);
      b1 = make_float2(c, s); b2 = cmul(b1, b1); b3 = cmul(b2, b1); }
    float2 q1, q2, q3;
    { float s, c; __sincosf(TWO_PI * (float)(l & 3) * (1.0f/16.0f), &s, &c);
      q1 = make_float2(c, s); q2 = cmul(q1, q1); q3 = cmul(q2, q1); }
    // Window weights for samples 2l+128o (x) / 2l+1+128o (y); Hann identity
    // ww[2]=2S-ww[0], ww[3]=2S-ww[1] keeps only o=0,1 persistent.
    const float S2 = 1.3020833333e-3f;    // 2 * 0.5/768
    float wwx0, wwx1, wwy0, wwy1;
    {
        const float S = 6.5104166667e-4f;   // 0.5/768
        float sx, cx; __sincosf(TWO_PI * (float)(2*l) * (1.0f/512.0f), &sx, &cx);
        wwx0 = S*(1.0f-cx); wwx1 = S*(1.0f+sx);
        float sy, cy; __sincosf(TWO_PI * (float)(2*l+1) * (1.0f/512.0f), &sy, &cy);
        wwy0 = S*(1.0f-cy); wwy1 = S*(1.0f+sy);
    }
    // Transpose layouts (float4 index; same index algebra as the proven
    // conflict-free b64 version).  r2 measured 3.07M bank-conflict cycles
    // (~3% of CU-cycles) on these b128 patterns -- known, minor; candidate
    // for a later round, not this one.
    const int a1w = l;                                        // + 64*t0
    const int a1r = (l & 15) + 64 * (l >> 4);                 // + 16*q
    const int a2w = (l & 15) + 20 * (l >> 4);                 // + 80*t1
    const int a2r = (l & 3) + 20 * ((l >> 2) & 3) + 80 * (l >> 4);   // + 4*r
    const int a3w = ((l >> 2) & 3) + 4 * (l >> 4) + 20 * (l & 3);    // + 80*t2
    const int a3r = (l & 3) + 4 * ((l >> 2) & 3) + 80 * (l >> 4);    // + 20*k0

    float accx[4], accy[4];
    #pragma unroll
    for (int o = 0; o < 4; ++o) { accx[o] = 0.0f; accy[o] = 0.0f; }

    // Raw prefetch registers for the next PAIR of frames.
    float dra[4], dia[4], mra[4], mia[4];
    float drb[4], dib[4], mrb[4], mib[4];

    auto issue_loads = [&](int fq) {           // frames fq (a) and fq+1 (b)
        const int fca = min(max(fq,     0), NFRAMES - 1);
        const int fcb = min(max(fq + 1, 0), NFRAMES - 1);
        const float* __restrict__ rba = reb + (size_t)fca * NBINS;
        const float* __restrict__ iba = imb + (size_t)fca * NBINS;
        const float* __restrict__ rbb = reb + (size_t)fcb * NBINS;
        const float* __restrict__ ibb = imb + (size_t)fcb * NBINS;
        #pragma unroll
        for (int j = 0; j < 4; ++j) {
            const int k = l + 64*j, km = 256 - k;
            dra[j] = rba[k];  dia[j] = iba[k];
            mra[j] = rba[km]; mia[j] = iba[km];
            drb[j] = rbb[k];  dib[j] = ibb[k];
            mrb[j] = rbb[km]; mib[j] = ibb[km];
        }
    };

    // Stage-1 math for one frame: pack + dft4 + w-twiddles -> A[4].
    auto s1frame = [&](const float* dr_, const float* di_,
                       const float* mr_, const float* mi_, float2* A) {
        float2 Cv[4];
        float cc = ctw0.x, ss = ctw0.y;   // walking twiddle, pi/4 per j-step
        #pragma unroll
        for (int j = 0; j < 4; ++j) {
            float ydr = dr_[j], ydi = di_[j], ymr = mr_[j], ymi = mi_[j];
            if (j == 0) {                       // k==0: Im of DC & Nyquist ignored
                const bool z = (l == 0);
                ydi = z ? 0.0f : ydi;
                ymi = z ? 0.0f : ymi;
            }
            const float er  = ydr + ymr, ei  = ydi - ymi;
            const float fr2 = ydr - ymr, fi2 = ydi + ymi;
            const float gr = cc*fr2 - ss*fi2;
            const float gi = cc*fi2 + ss*fr2;
            Cv[j] = make_float2(er - gi, ei + gr);
            const float cn = (cc - ss) * RQ, sn = (ss + cc) * RQ;  // rotate pi/4
            cc = cn; ss = sn;
        }
        dft4(Cv, A);
        A[1] = cmul(A[1], w1); A[2] = cmul(A[2], w2); A[3] = cmul(A[3], w3);
    };

    auto stage1 = [&](float4* __restrict__ P) {
        float2 Aa[4], Ab[4];
        s1frame(dra, dia, mra, mia, Aa);
        s1frame(drb, dib, mrb, mib, Ab);
        #pragma unroll
        for (int j = 0; j < 4; ++j)
            P[a1w + 64*j] = make_float4(Aa[j].x, Aa[j].y, Ab[j].x, Ab[j].y);
    };

    auto stages234 = [&](float4* __restrict__ P, int fa) {
        float2 Ga[4], Gb[4], Aa[4], Ab[4];
        // ---- stage 2 ----
        #pragma unroll
        for (int t = 0; t < 4; ++t) {
            const float4 g = P[a1r + 16*t];
            Ga[t] = make_float2(g.x, g.y); Gb[t] = make_float2(g.z, g.w);
        }
        dft4(Ga, Aa); dft4(Gb, Ab);
        Aa[1]=cmul(Aa[1],b1); Aa[2]=cmul(Aa[2],b2); Aa[3]=cmul(Aa[3],b3);
        Ab[1]=cmul(Ab[1],b1); Ab[2]=cmul(Ab[2],b2); Ab[3]=cmul(Ab[3],b3);
        #pragma unroll
        for (int t = 0; t < 4; ++t)
            P[a2w + 80*t] = make_float4(Aa[t].x, Aa[t].y, Ab[t].x, Ab[t].y);
        // ---- stage 3 ----
        #pragma unroll
        for (int t = 0; t < 4; ++t) {
            const float4 g = P[a2r + 4*t];
            Ga[t] = make_float2(g.x, g.y); Gb[t] = make_float2(g.z, g.w);
        }
        dft4(Ga, Aa); dft4(Gb, Ab);
        Aa[1]=cmul(Aa[1],q1); Aa[2]=cmul(Aa[2],q2); Aa[3]=cmul(Aa[3],q3);
        Ab[1]=cmul(Ab[1],q1); Ab[2]=cmul(Ab[2],q2); Ab[3]=cmul(Ab[3],q3);
        #pragma unroll
        for (int t = 0; t < 4; ++t)
            P[a3w + 80*t] = make_float4(Aa[t].x, Aa[t].y, Ab[t].x, Ab[t].y);
        // ---- stage 4 ----
        #pragma unroll
        for (int t = 0; t < 4; ++t) {
            const float4 g = P[a3r + 20*t];
            Ga[t] = make_float2(g.x, g.y); Gb[t] = make_float2(g.z, g.w);
        }
        dft4(Ga, Aa); dft4(Gb, Ab);
        // ---- OLA: frame fa first (chunk fa must NOT see frame fb), then fb ----
        const int fb = fa + 1;
        if (fa >= 0 && fa < NFRAMES) {          // wave-uniform gate
            accx[0] = fmaf(Aa[0].x, wwx0, accx[0]);
            accx[1] = fmaf(Aa[1].x, wwx1, accx[1]);
            accx[2] = fmaf(Aa[2].x, S2, fmaf(-Aa[2].x, wwx0, accx[2]));
            accx[3] = fmaf(Aa[3].x, S2, fmaf(-Aa[3].x, wwx1, accx[3]));
            accy[0] = fmaf(Aa[0].y, wwy0, accy[0]);
            accy[1] = fmaf(Aa[1].y, wwy1, accy[1]);
            accy[2] = fmaf(Aa[2].y, S2, fmaf(-Aa[2].y, wwy0, accy[2]));
            accy[3] = fmaf(Aa[3].y, S2, fmaf(-Aa[3].y, wwy1, accy[3]));
        }
        if (fa >= c0 && fa <= fend) {           // emit chunk fa (complete now)
            const int s0 = fa * HOP + 2*l;      // max 512382 < OUT_LEN
            outb[s0] = accx[0];
            const int s1 = s0 + 1;
            if (s1 < OUT_LEN) outb[s1] = accy[0];
        }
        #pragma unroll
        for (int o = 0; o < 3; ++o) { accx[o] = accx[o+1]; accy[o] = accy[o+1]; }
        accx[3] = 0.0f; accy[3] = 0.0f;
        if (fb >= 0 && fb < NFRAMES) {
            accx[0] = fmaf(Ab[0].x, wwx0, accx[0]);
            accx[1] = fmaf(Ab[1].x, wwx1, accx[1]);
            accx[2] = fmaf(Ab[2].x, S2, fmaf(-Ab[2].x, wwx0, accx[2]));
            accx[3] = fmaf(Ab[3].x, S2, fmaf(-Ab[3].x, wwx1, accx[3]));
            accy[0] = fmaf(Ab[0].y, wwy0, accy[0]);
            accy[1] = fmaf(Ab[1].y, wwy1, accy[1]);
            accy[2] = fmaf(Ab[2].y, S2, fmaf(-Ab[2].y, wwy0, accy[2]));
            accy[3] = fmaf(Ab[3].y, S2, fmaf(-Ab[3].y, wwy1, accy[3]));
        }
        if (fb >= c0 && fb <= fend) {
            const int s0 = fb * HOP + 2*l;
            outb[s0] = accx[0];
            const int s1 = s0 + 1;
            if (s1 < OUT_LEN) outb[s1] = accy[0];
        }
        #pragma unroll
        for (int o = 0; o < 3; ++o) { accx[o] = accx[o+1]; accy[o] = accy[o+1]; }
        accx[3] = 0.0f; accy[3] = 0.0f;
    };

    // ---- software-pipelined pair loop: 6 pairs = frames c0-4 .. c0+7 ----
    // (frame c0-4 contributes only to chunks < c0: harmless 1-frame halo waste;
    //  frames > fend are load-clamped + acc/emit-gated.)
    const int base = c0 - 4;
    issue_loads(base);
    stage1(PA);
    #pragma unroll 1
    for (int p = 0; p < 6; p += 2) {
        issue_loads(base + 2*(p+1));   // in flight during stages234(pair p)
        stages234(PA, base + 2*p);
        stage1(PBp);                   // consumes pair p+1 loads
        if (p + 2 < 6) issue_loads(base + 2*(p+2));
        stages234(PBp, base + 2*(p+1));
        if (p + 2 < 6) stage1(PA);
    }
}

extern "C" void kernel_launch(void* const* d_in, const int* in_sizes, int n_in,
                              void* d_out, int out_size, void* d_ws, size_t ws_size,
                              hipStream_t stream) {
    (void)in_sizes; (void)n_in; (void)d_ws; (void)ws_size; (void)out_size;
    const float* re = (const float*)d_in[0];
    const float* im = (const float*)d_in[1];
    float* out = (float*)d_out;

    // 16 batches x 501 ranges = 8016 waves; 4 waves per 256-thread block.
    const int nblocks = (NB * RPB) / 4;   // 2004
    istft_pk4_kernel<<<dim3(nblocks), dim3(256), 0, stream>>>(re, im, out);
}